// Round 1
// baseline (209.056 us; speedup 1.0000x reference)
//
#include <hip/hip_runtime.h>
#include <math.h>

#define NSITES 131072      // 32*16*16*16

struct cplx { float re, im; };

__device__ __forceinline__ cplx cadd(cplx a, cplx b) { return {a.re + b.re, a.im + b.im}; }
__device__ __forceinline__ cplx cmul(cplx a, cplx b) {
    return { fmaf(a.re, b.re, -(a.im * b.im)), fmaf(a.re, b.im, a.im * b.re) };
}

// 12-byte vector load/store (global_load_dwordx3); rows are 36 B so only 4B-aligned
struct __attribute__((aligned(4))) f3 { float x, y, z; };
__device__ __forceinline__ void ld9(const float* __restrict__ p, float* r) {
    f3 a = *(const f3*)p, b = *(const f3*)(p + 3), c = *(const f3*)(p + 6);
    r[0] = a.x; r[1] = a.y; r[2] = a.z;
    r[3] = b.x; r[4] = b.y; r[5] = b.z;
    r[6] = c.x; r[7] = c.y; r[8] = c.z;
}

// async global->LDS DMA; LDS dest = wave-uniform base + lane*size
#define GLDS16(g, l) __builtin_amdgcn_global_load_lds( \
    (const __attribute__((address_space(1))) void*)(g), \
    (__attribute__((address_space(3))) void*)(l), 16, 0, 0)
#define GLDS4(g, l) __builtin_amdgcn_global_load_lds( \
    (const __attribute__((address_space(1))) void*)(g), \
    (__attribute__((address_space(3))) void*)(l), 4, 0, 0)

// Stage one 4608-B wave slab: 8 features x 16 sites x 36 B (one of re/im plane).
// 16B pieces cover bytes 0..4095 (chunks 0..6 full + chunk 7 head);
// 2 x 4B ops cover chunk 7 bytes 64..575 (tail 512 B).
__device__ __forceinline__ void stage_slab(const char* __restrict__ base,
                                           char* lds, int wsite, int lane)
{
    #pragma unroll
    for (int k = 0; k < 4; k++) {
        int p   = k * 64 + lane;            // 16B piece index 0..255
        int c   = p / 36;                   // feature chunk 0..7 (576 B each)
        int off = (p - c * 36) * 16;        // byte offset within chunk
        const char* g = base + (size_t)(c * NSITES + wsite) * 36 + off;
        GLDS16(g, lds + k * 1024);
    }
    #pragma unroll
    for (int k = 0; k < 2; k++) {
        int off = 64 + 4 * (k * 64 + lane); // chunk 7, bytes 64..572
        const char* g = base + (size_t)(7 * NSITES + wsite) * 36 + off;
        GLDS4(g, lds + 4096 + k * 256);
    }
}

// V = E*M column product using the 8-DOF anti-hermitian E:
//  E = [[i*ed0, er01+i*ei01, er02+i*ei02],
//       [-er01+i*ei01, i*ed1, er12+i*ei12],
//       [-er02+i*ei02, -er12+i*ei12, i*ed2]]
#define ECOL(m0, m1, m2, v0, v1, v2) do { \
    v0.re = fmaf(-ed0, m0.im, fmaf(er01, m1.re, fmaf(-ei01, m1.im, fmaf(er02, m2.re, -(ei02 * m2.im))))); \
    v0.im = fmaf( ed0, m0.re, fmaf(er01, m1.im, fmaf( ei01, m1.re, fmaf(er02, m2.im,  (ei02 * m2.re))))); \
    v1.re = fmaf(-er01, m0.re, fmaf(-ei01, m0.im, fmaf(-ed1, m1.im, fmaf(er12, m2.re, -(ei12 * m2.im))))); \
    v1.im = fmaf(-er01, m0.im, fmaf( ei01, m0.re, fmaf( ed1, m1.re, fmaf(er12, m2.im,  (ei12 * m2.re))))); \
    v2.re = fmaf(-er02, m0.re, fmaf(-ei02, m0.im, fmaf(-er12, m1.re, fmaf(-ei12, m1.im, -(ed2 * m2.im))))); \
    v2.im = fmaf(-er02, m0.im, fmaf( ei02, m0.re, fmaf(-er12, m1.im, fmaf( ei12, m1.re,  (ed2 * m2.re))))); \
} while (0)

// real part of g0*m + g1*v + g2*z
#define OCOMB(m, v, z) \
    fmaf(g0.re, m.re, fmaf(-g0.im, m.im, fmaf(g1.re, v.re, fmaf(-g1.im, v.im, \
    fmaf(g2.re, z.re, -(g2.im * z.im))))))

// Block = 256 thr = 4 waves, 64 sites, all 4 mu. Wave-private two-phase LDS
// staging (re plane, then im plane into the SAME 4608-B slab) halves LDS to
// 18,432 B/block -> 8 blocks/CU -> 8 waves/SIMD. No __syncthreads anywhere.
__global__ __launch_bounds__(256, 8) void lge_exp_kernel(
    const float* __restrict__ U_re, const float* __restrict__ U_im,
    const float* __restrict__ W_re, const float* __restrict__ W_im,
    const float* __restrict__ ahw,  float* __restrict__ out)
{
    __shared__ __align__(16) float Wl[4 * 1152];   // 4 waves x 4608 B = 18,432 B

    const int tid   = threadIdx.x;
    const int w     = tid >> 6;        // wave id in block
    const int lane  = tid & 63;
    const int site0 = blockIdx.x << 6; // 64 sites per block
    const int wsite = site0 + 16 * w;

    float* ldsw = Wl + w * 1152;

    // ---- phase 1 staging: W_re slab (6 DMA ops) ----
    stage_slab((const char*)W_re, (char*)ldsw, wsite, lane);

    const int siteL = lane >> 2;               // 0..15 within wave tile
    const int mu    = lane & 3;
    const int gsite = wsite + siteL;

    // ahw row for this mu (drained by the same vmcnt wait)
    const float4* ahw4 = (const float4*)ahw;
    float4 wlo = ahw4[mu * 2], whi = ahw4[mu * 2 + 1];
    const float wfv[8] = { wlo.x, wlo.y, wlo.z, wlo.w, whi.x, whi.y, whi.z, whi.w };

    asm volatile("" ::: "memory");
    __builtin_amdgcn_s_waitcnt(0);     // drain this wave's W_re DMA
    asm volatile("" ::: "memory");

    // ---- E real part: antisymmetric, 3 DOF. Re(W-W^dag) has zero diagonal
    //      and no trace correction -> only 3 accumulators, 6 LDS reads/feature.
    const float* wp = ldsw + siteL * 9;        // + f*144
    float er01 = 0.f, er02 = 0.f, er12 = 0.f;
    #pragma unroll
    for (int f = 0; f < 8; f++) {
        const float* r = wp + f * 144;
        float wf = wfv[f];
        er01 = fmaf(wf, r[1] - r[3], er01);
        er02 = fmaf(wf, r[2] - r[6], er02);
        er12 = fmaf(wf, r[5] - r[7], er12);
    }

    // all phase-1 ds_reads must retire before the W_im DMA overwrites the slab
    asm volatile("s_waitcnt lgkmcnt(0)" ::: "memory");

    // ---- phase 2 staging: W_im slab into the same buffer ----
    stage_slab((const char*)W_im, (char*)ldsw, wsite, lane);

    // U loads issued now; drained with the same vmcnt wait, consumed at the end
    const int ub = (mu * NSITES + gsite) * 9;
    float ur[9], ui[9];
    ld9(U_re + ub, ur);
    ld9(U_im + ub, ui);

    asm volatile("" ::: "memory");
    __builtin_amdgcn_s_waitcnt(0);     // drain W_im DMA (+ U loads)
    asm volatile("" ::: "memory");

    // ---- E imag part: symmetric traceless, 5 DOF. Raw-accumulate 9 sums,
    //      combine once at the end.
    float a0=0.f,a1=0.f,a2=0.f,a3=0.f,a4=0.f,a5=0.f,a6=0.f,a7=0.f,a8=0.f;
    #pragma unroll
    for (int f = 0; f < 8; f++) {
        const float* r = wp + f * 144;
        float wf = wfv[f];
        a0 = fmaf(wf, r[0], a0); a1 = fmaf(wf, r[1], a1); a2 = fmaf(wf, r[2], a2);
        a3 = fmaf(wf, r[3], a3); a4 = fmaf(wf, r[4], a4); a5 = fmaf(wf, r[5], a5);
        a6 = fmaf(wf, r[6], a6); a7 = fmaf(wf, r[7], a7); a8 = fmaf(wf, r[8], a8);
    }
    const float ei01 = a1 + a3, ei02 = a2 + a6, ei12 = a5 + a7;
    const float t3  = (a0 + a4 + a8) * (2.f / 3.f);
    const float ed0 = fmaf(2.f, a0, -t3);
    const float ed1 = fmaf(2.f, a4, -t3);
    const float ed2 = fmaf(2.f, a8, -t3);       // == -ed0-ed1

    // ---- ||E||_F^2 ; p = tr(E^2)/2 = -r2/2 (REAL, free) ----
    float r2 = fmaf(er01, er01, fmaf(er02, er02, fmaf(er12, er12,
               fmaf(ei01, ei01, fmaf(ei02, ei02, ei12 * ei12)))));
    r2 = fmaf(2.f, r2, fmaf(ed0, ed0, fmaf(ed1, ed1, ed2 * ed2)));

    // ---- q = det(E) = -i*det(H), H = -iE hermitian -> q purely imaginary ----
    // h01=(ei01,-er01) h02=(ei02,-er02) h12=(ei12,-er12), diag = ed*
    const float n01 = fmaf(ei01, ei01, er01 * er01);
    const float n02 = fmaf(ei02, ei02, er02 * er02);
    const float n12 = fmaf(ei12, ei12, er12 * er12);
    const float zre = fmaf(ei01, ei12, -(er01 * er12));   // Re(h01*h12)
    const float zim = -fmaf(ei01, er12, er01 * ei12);     // Im(h01*h12)
    const float detH = ed0 * ed1 * ed2
                     + 2.f * fmaf(zre, ei02, -(zim * er02))
                     - fmaf(ed0, n12, fmaf(ed1, n02, ed2 * n01));

    // ---- scaling: 2^sc >= 2*||E||_F >= 2*rho(E), from exponent bits of r2 ----
    int e; (void)frexpf(r2, &e);                 // r2 = m*2^e, m in [0.5,1)
    int sc = (e <= -2) ? 0 : min(1 + ((e + 1) >> 1), 40);
    const float inv  = __int_as_float((127 - sc) << 23);   // 2^-sc
    const float inv2 = inv * inv;
    const float px   = -0.5f * r2 * inv2;        // p of scaled X (real)
    const float qxi  = -detH * (inv2 * inv);     // q of scaled X = i*qxi

    // ---- Taylor of exp(X) in coefficient space (p real, q imaginary) ----
    cplx T0 = {1.f, 0.f}, T1 = {0.f, 0.f}, T2 = {0.f, 0.f};
    cplx S0 = {1.f, 0.f}, S1 = {0.f, 0.f}, S2 = {0.f, 0.f};
    #pragma unroll
    for (int n = 1; n <= 10; n++) {
        float c  = 1.f / (float)n;               // folds to a literal
        float qc = qxi * c;
        cplx nT0 = { -qc * T2.im, qc * T2.re };
        cplx nT1 = { c * fmaf(px, T2.re, T0.re), c * fmaf(px, T2.im, T0.im) };
        cplx nT2 = { c * T1.re, c * T1.im };
        T0 = nT0; T1 = nT1; T2 = nT2;
        S0 = cadd(S0, T0); S1 = cadd(S1, T1); S2 = cadd(S2, T2);
    }

    // ---- repeated squaring in coefficient space ----
    const float q2 = 2.f * qxi;
    for (int k = 0; k < sc; k++) {
        cplx f0 = S0, f1 = S1, f2 = S2;
        cplx f12 = cmul(f1, f2);
        cplx f01 = cmul(f0, f1);
        cplx f02 = cmul(f0, f2);
        float f00re = fmaf(f0.re, f0.re, -(f0.im * f0.im)), f00im = 2.f * f0.re * f0.im;
        float f11re = fmaf(f1.re, f1.re, -(f1.im * f1.im)), f11im = 2.f * f1.re * f1.im;
        float f22re = fmaf(f2.re, f2.re, -(f2.im * f2.im)), f22im = 2.f * f2.re * f2.im;
        S0.re = fmaf(-q2, f12.im, f00re);
        S0.im = fmaf( q2, f12.re, f00im);
        S1.re = fmaf(-qxi, f22im, 2.f * fmaf(px, f12.re, f01.re));
        S1.im = fmaf( qxi, f22re, 2.f * fmaf(px, f12.im, f01.im));
        S2.re = fmaf(px, f22re, fmaf(2.f, f02.re, f11re));
        S2.im = fmaf(px, f22im, fmaf(2.f, f02.im, f11im));
    }
    const cplx g0 = S0;
    const cplx g1 = { S1.re * inv,  S1.im * inv  };
    const cplx g2 = { S2.re * inv2, S2.im * inv2 };

    // ---- apply: out = Re[ g0 U + g1 (E U) + g2 (E (E U)) ], column-wise ----
    float o[9];
    #pragma unroll
    for (int b = 0; b < 3; b++) {
        cplx m0 = { ur[b],     ui[b]     };
        cplx m1 = { ur[3 + b], ui[3 + b] };
        cplx m2 = { ur[6 + b], ui[6 + b] };
        cplx v0, v1, v2, z0, z1, z2;
        ECOL(m0, m1, m2, v0, v1, v2);   // V col = E * U col
        ECOL(v0, v1, v2, z0, z1, z2);   // Z col = E * V col
        o[b]     = OCOMB(m0, v0, z0);
        o[3 + b] = OCOMB(m1, v1, z1);
        o[6 + b] = OCOMB(m2, v2, z2);
    }

    float* ob = out + ub;
    *(f3*)(ob)     = { o[0], o[1], o[2] };
    *(f3*)(ob + 3) = { o[3], o[4], o[5] };
    *(f3*)(ob + 6) = { o[6], o[7], o[8] };
}

extern "C" void kernel_launch(void* const* d_in, const int* in_sizes, int n_in,
                              void* d_out, int out_size, void* d_ws, size_t ws_size,
                              hipStream_t stream) {
    const float* U_re = (const float*)d_in[0];
    const float* U_im = (const float*)d_in[1];
    const float* W_re = (const float*)d_in[2];
    const float* W_im = (const float*)d_in[3];
    const float* ahw  = (const float*)d_in[4];
    float* out = (float*)d_out;
    // 2048 blocks x 64 sites; each block computes all 4 mu for its sites.
    // 18,432 B LDS/block -> 8 blocks/CU resident = full grid co-resident.
    lge_exp_kernel<<<dim3(NSITES / 64), dim3(256), 0, stream>>>(
        U_re, U_im, W_re, W_im, ahw, out);
}

// Round 2
// 163.346 us; speedup vs baseline: 1.2798x; 1.2798x over previous
//
#include <hip/hip_runtime.h>
#include <math.h>

#define NSITES 131072      // 32*16*16*16

struct cplx { float re, im; };

__device__ __forceinline__ cplx cadd(cplx a, cplx b) { return {a.re + b.re, a.im + b.im}; }
__device__ __forceinline__ cplx cmul(cplx a, cplx b) {
    return { fmaf(a.re, b.re, -(a.im * b.im)), fmaf(a.re, b.im, a.im * b.re) };
}

// 12-byte vector load/store (global_load_dwordx3); rows are 36 B so only 4B-aligned
struct __attribute__((aligned(4))) f3 { float x, y, z; };
__device__ __forceinline__ void ld9(const float* __restrict__ p, float* r) {
    f3 a = *(const f3*)p, b = *(const f3*)(p + 3), c = *(const f3*)(p + 6);
    r[0] = a.x; r[1] = a.y; r[2] = a.z;
    r[3] = b.x; r[4] = b.y; r[5] = b.z;
    r[6] = c.x; r[7] = c.y; r[8] = c.z;
}

// async global->LDS DMA; LDS dest = wave-uniform base + lane*size
#define GLDS16(g, l) __builtin_amdgcn_global_load_lds( \
    (const __attribute__((address_space(1))) void*)(g), \
    (__attribute__((address_space(3))) void*)(l), 16, 0, 0)
#define GLDS4(g, l) __builtin_amdgcn_global_load_lds( \
    (const __attribute__((address_space(1))) void*)(g), \
    (__attribute__((address_space(3))) void*)(l), 4, 0, 0)

// Stage one 4608-B wave slab: 8 features x 16 sites x 36 B (one of re/im plane).
// 16B pieces cover bytes 0..4095 (chunks 0..6 full + chunk 7 head);
// 2 x 4B ops cover chunk 7 bytes 64..575 (tail 512 B).
__device__ __forceinline__ void stage_slab(const char* __restrict__ base,
                                           char* lds, int wsite, int lane)
{
    #pragma unroll
    for (int k = 0; k < 4; k++) {
        int p   = k * 64 + lane;            // 16B piece index 0..255
        int c   = p / 36;                   // feature chunk 0..7 (576 B each)
        int off = (p - c * 36) * 16;        // byte offset within chunk
        const char* g = base + (size_t)(c * NSITES + wsite) * 36 + off;
        GLDS16(g, lds + k * 1024);
    }
    #pragma unroll
    for (int k = 0; k < 2; k++) {
        int off = 64 + 4 * (k * 64 + lane); // chunk 7, bytes 64..572
        const char* g = base + (size_t)(7 * NSITES + wsite) * 36 + off;
        GLDS4(g, lds + 4096 + k * 256);
    }
}

// V = E*M column product using the 8-DOF anti-hermitian E:
//  E = [[i*ed0, er01+i*ei01, er02+i*ei02],
//       [-er01+i*ei01, i*ed1, er12+i*ei12],
//       [-er02+i*ei02, -er12+i*ei12, i*ed2]]
#define ECOL(m0, m1, m2, v0, v1, v2) do { \
    v0.re = fmaf(-ed0, m0.im, fmaf(er01, m1.re, fmaf(-ei01, m1.im, fmaf(er02, m2.re, -(ei02 * m2.im))))); \
    v0.im = fmaf( ed0, m0.re, fmaf(er01, m1.im, fmaf( ei01, m1.re, fmaf(er02, m2.im,  (ei02 * m2.re))))); \
    v1.re = fmaf(-er01, m0.re, fmaf(-ei01, m0.im, fmaf(-ed1, m1.im, fmaf(er12, m2.re, -(ei12 * m2.im))))); \
    v1.im = fmaf(-er01, m0.im, fmaf( ei01, m0.re, fmaf( ed1, m1.re, fmaf(er12, m2.im,  (ei12 * m2.re))))); \
    v2.re = fmaf(-er02, m0.re, fmaf(-ei02, m0.im, fmaf(-er12, m1.re, fmaf(-ei12, m1.im, -(ed2 * m2.im))))); \
    v2.im = fmaf(-er02, m0.im, fmaf( ei02, m0.re, fmaf(-er12, m1.im, fmaf( ei12, m1.re,  (ed2 * m2.re))))); \
} while (0)

// real part of g0*m + g1*v + g2*z
#define OCOMB(m, v, z) \
    fmaf(g0.re, m.re, fmaf(-g0.im, m.im, fmaf(g1.re, v.re, fmaf(-g1.im, v.im, \
    fmaf(g2.re, z.re, -(g2.im * z.im))))))

// Block = 256 thr = 4 waves, 64 sites, all 4 mu. Wave-private two-phase LDS
// staging (re plane, then im plane into the SAME 4608-B slab) halves LDS to
// 18,432 B/block -> 8 blocks/CU possible. Occupancy bound = 6 waves/EU:
// (256,8) capped VGPRs at 64 and caused catastrophic scratch spill
// (WRITE_SIZE 18.5 MB -> 155 MB, dur 45 -> 110 us). 512/6 = 85 VGPRs is
// comfortable (the Round-0 kernel with MORE live state fit in 64).
__global__ __launch_bounds__(256, 6) void lge_exp_kernel(
    const float* __restrict__ U_re, const float* __restrict__ U_im,
    const float* __restrict__ W_re, const float* __restrict__ W_im,
    const float* __restrict__ ahw,  float* __restrict__ out)
{
    __shared__ __align__(16) float Wl[4 * 1152];   // 4 waves x 4608 B = 18,432 B

    const int tid   = threadIdx.x;
    const int w     = tid >> 6;        // wave id in block
    const int lane  = tid & 63;
    const int site0 = blockIdx.x << 6; // 64 sites per block
    const int wsite = site0 + 16 * w;

    float* ldsw = Wl + w * 1152;

    // ---- phase 1 staging: W_re slab (6 DMA ops) ----
    stage_slab((const char*)W_re, (char*)ldsw, wsite, lane);

    const int siteL = lane >> 2;               // 0..15 within wave tile
    const int mu    = lane & 3;
    const int gsite = wsite + siteL;

    // ahw row for this mu (drained by the same vmcnt wait)
    const float4* ahw4 = (const float4*)ahw;
    float4 wlo = ahw4[mu * 2], whi = ahw4[mu * 2 + 1];
    const float wfv[8] = { wlo.x, wlo.y, wlo.z, wlo.w, whi.x, whi.y, whi.z, whi.w };

    asm volatile("" ::: "memory");
    __builtin_amdgcn_s_waitcnt(0);     // drain this wave's W_re DMA
    asm volatile("" ::: "memory");

    // ---- E real part: antisymmetric, 3 DOF. Re(W-W^dag) has zero diagonal
    //      and no trace correction -> only 3 accumulators, 6 LDS reads/feature.
    const float* wp = ldsw + siteL * 9;        // + f*144
    float er01 = 0.f, er02 = 0.f, er12 = 0.f;
    #pragma unroll
    for (int f = 0; f < 8; f++) {
        const float* r = wp + f * 144;
        float wf = wfv[f];
        er01 = fmaf(wf, r[1] - r[3], er01);
        er02 = fmaf(wf, r[2] - r[6], er02);
        er12 = fmaf(wf, r[5] - r[7], er12);
    }

    // all phase-1 ds_reads must retire before the W_im DMA overwrites the slab
    asm volatile("s_waitcnt lgkmcnt(0)" ::: "memory");

    // ---- phase 2 staging: W_im slab into the same buffer ----
    stage_slab((const char*)W_im, (char*)ldsw, wsite, lane);

    // U loads issued now; drained with the same vmcnt wait, consumed at the end
    const int ub = (mu * NSITES + gsite) * 9;
    float ur[9], ui[9];
    ld9(U_re + ub, ur);
    ld9(U_im + ub, ui);

    asm volatile("" ::: "memory");
    __builtin_amdgcn_s_waitcnt(0);     // drain W_im DMA (+ U loads)
    asm volatile("" ::: "memory");

    // ---- E imag part: symmetric traceless, 5 DOF. Raw-accumulate 9 sums,
    //      combine once at the end.
    float a0=0.f,a1=0.f,a2=0.f,a3=0.f,a4=0.f,a5=0.f,a6=0.f,a7=0.f,a8=0.f;
    #pragma unroll
    for (int f = 0; f < 8; f++) {
        const float* r = wp + f * 144;
        float wf = wfv[f];
        a0 = fmaf(wf, r[0], a0); a1 = fmaf(wf, r[1], a1); a2 = fmaf(wf, r[2], a2);
        a3 = fmaf(wf, r[3], a3); a4 = fmaf(wf, r[4], a4); a5 = fmaf(wf, r[5], a5);
        a6 = fmaf(wf, r[6], a6); a7 = fmaf(wf, r[7], a7); a8 = fmaf(wf, r[8], a8);
    }
    const float ei01 = a1 + a3, ei02 = a2 + a6, ei12 = a5 + a7;
    const float t3  = (a0 + a4 + a8) * (2.f / 3.f);
    const float ed0 = fmaf(2.f, a0, -t3);
    const float ed1 = fmaf(2.f, a4, -t3);
    const float ed2 = fmaf(2.f, a8, -t3);       // == -ed0-ed1

    // ---- ||E||_F^2 ; p = tr(E^2)/2 = -r2/2 (REAL, free) ----
    float r2 = fmaf(er01, er01, fmaf(er02, er02, fmaf(er12, er12,
               fmaf(ei01, ei01, fmaf(ei02, ei02, ei12 * ei12)))));
    r2 = fmaf(2.f, r2, fmaf(ed0, ed0, fmaf(ed1, ed1, ed2 * ed2)));

    // ---- q = det(E) = -i*det(H), H = -iE hermitian -> q purely imaginary ----
    // h01=(ei01,-er01) h02=(ei02,-er02) h12=(ei12,-er12), diag = ed*
    const float n01 = fmaf(ei01, ei01, er01 * er01);
    const float n02 = fmaf(ei02, ei02, er02 * er02);
    const float n12 = fmaf(ei12, ei12, er12 * er12);
    const float zre = fmaf(ei01, ei12, -(er01 * er12));   // Re(h01*h12)
    const float zim = -fmaf(ei01, er12, er01 * ei12);     // Im(h01*h12)
    const float detH = ed0 * ed1 * ed2
                     + 2.f * fmaf(zre, ei02, -(zim * er02))
                     - fmaf(ed0, n12, fmaf(ed1, n02, ed2 * n01));

    // ---- scaling: 2^sc >= 2*||E||_F >= 2*rho(E), from exponent bits of r2 ----
    int e; (void)frexpf(r2, &e);                 // r2 = m*2^e, m in [0.5,1)
    int sc = (e <= -2) ? 0 : min(1 + ((e + 1) >> 1), 40);
    const float inv  = __int_as_float((127 - sc) << 23);   // 2^-sc
    const float inv2 = inv * inv;
    const float px   = -0.5f * r2 * inv2;        // p of scaled X (real)
    const float qxi  = -detH * (inv2 * inv);     // q of scaled X = i*qxi

    // ---- Taylor of exp(X) in coefficient space (p real, q imaginary) ----
    cplx T0 = {1.f, 0.f}, T1 = {0.f, 0.f}, T2 = {0.f, 0.f};
    cplx S0 = {1.f, 0.f}, S1 = {0.f, 0.f}, S2 = {0.f, 0.f};
    #pragma unroll
    for (int n = 1; n <= 10; n++) {
        float c  = 1.f / (float)n;               // folds to a literal
        float qc = qxi * c;
        cplx nT0 = { -qc * T2.im, qc * T2.re };
        cplx nT1 = { c * fmaf(px, T2.re, T0.re), c * fmaf(px, T2.im, T0.im) };
        cplx nT2 = { c * T1.re, c * T1.im };
        T0 = nT0; T1 = nT1; T2 = nT2;
        S0 = cadd(S0, T0); S1 = cadd(S1, T1); S2 = cadd(S2, T2);
    }

    // ---- repeated squaring in coefficient space ----
    const float q2 = 2.f * qxi;
    for (int k = 0; k < sc; k++) {
        cplx f0 = S0, f1 = S1, f2 = S2;
        cplx f12 = cmul(f1, f2);
        cplx f01 = cmul(f0, f1);
        cplx f02 = cmul(f0, f2);
        float f00re = fmaf(f0.re, f0.re, -(f0.im * f0.im)), f00im = 2.f * f0.re * f0.im;
        float f11re = fmaf(f1.re, f1.re, -(f1.im * f1.im)), f11im = 2.f * f1.re * f1.im;
        float f22re = fmaf(f2.re, f2.re, -(f2.im * f2.im)), f22im = 2.f * f2.re * f2.im;
        S0.re = fmaf(-q2, f12.im, f00re);
        S0.im = fmaf( q2, f12.re, f00im);
        S1.re = fmaf(-qxi, f22im, 2.f * fmaf(px, f12.re, f01.re));
        S1.im = fmaf( qxi, f22re, 2.f * fmaf(px, f12.im, f01.im));
        S2.re = fmaf(px, f22re, fmaf(2.f, f02.re, f11re));
        S2.im = fmaf(px, f22im, fmaf(2.f, f02.im, f11im));
    }
    const cplx g0 = S0;
    const cplx g1 = { S1.re * inv,  S1.im * inv  };
    const cplx g2 = { S2.re * inv2, S2.im * inv2 };

    // ---- apply: out = Re[ g0 U + g1 (E U) + g2 (E (E U)) ], column-wise ----
    float o[9];
    #pragma unroll
    for (int b = 0; b < 3; b++) {
        cplx m0 = { ur[b],     ui[b]     };
        cplx m1 = { ur[3 + b], ui[3 + b] };
        cplx m2 = { ur[6 + b], ui[6 + b] };
        cplx v0, v1, v2, z0, z1, z2;
        ECOL(m0, m1, m2, v0, v1, v2);   // V col = E * U col
        ECOL(v0, v1, v2, z0, z1, z2);   // Z col = E * V col
        o[b]     = OCOMB(m0, v0, z0);
        o[3 + b] = OCOMB(m1, v1, z1);
        o[6 + b] = OCOMB(m2, v2, z2);
    }

    float* ob = out + ub;
    *(f3*)(ob)     = { o[0], o[1], o[2] };
    *(f3*)(ob + 3) = { o[3], o[4], o[5] };
    *(f3*)(ob + 6) = { o[6], o[7], o[8] };
}

extern "C" void kernel_launch(void* const* d_in, const int* in_sizes, int n_in,
                              void* d_out, int out_size, void* d_ws, size_t ws_size,
                              hipStream_t stream) {
    const float* U_re = (const float*)d_in[0];
    const float* U_im = (const float*)d_in[1];
    const float* W_re = (const float*)d_in[2];
    const float* W_im = (const float*)d_in[3];
    const float* ahw  = (const float*)d_in[4];
    float* out = (float*)d_out;
    // 2048 blocks x 64 sites; each block computes all 4 mu for its sites
    lge_exp_kernel<<<dim3(NSITES / 64), dim3(256), 0, stream>>>(
        U_re, U_im, W_re, W_im, ahw, out);
}

// Round 3
// 145.559 us; speedup vs baseline: 1.4362x; 1.1222x over previous
//
#include <hip/hip_runtime.h>
#include <math.h>

#define NSITES 131072      // 32*16*16*16

struct cplx { float re, im; };

__device__ __forceinline__ cplx cadd(cplx a, cplx b) { return {a.re + b.re, a.im + b.im}; }
__device__ __forceinline__ cplx cmul(cplx a, cplx b) {
    return { fmaf(a.re, b.re, -(a.im * b.im)), fmaf(a.re, b.im, a.im * b.re) };
}

// 12-byte vector load/store (global_load_dwordx3); rows are 36 B so only 4B-aligned
struct __attribute__((aligned(4))) f3 { float x, y, z; };
__device__ __forceinline__ void ld9(const float* __restrict__ p, float* r) {
    f3 a = *(const f3*)p, b = *(const f3*)(p + 3), c = *(const f3*)(p + 6);
    r[0] = a.x; r[1] = a.y; r[2] = a.z;
    r[3] = b.x; r[4] = b.y; r[5] = b.z;
    r[6] = c.x; r[7] = c.y; r[8] = c.z;
}

// async global->LDS DMA; LDS dest = wave-uniform base + lane*size
#define GLDS16(g, l) __builtin_amdgcn_global_load_lds( \
    (const __attribute__((address_space(1))) void*)(g), \
    (__attribute__((address_space(3))) void*)(l), 16, 0, 0)
#define GLDS4(g, l) __builtin_amdgcn_global_load_lds( \
    (const __attribute__((address_space(1))) void*)(g), \
    (__attribute__((address_space(3))) void*)(l), 4, 0, 0)

// Stage one 4608-B wave slab: 8 features x 16 sites x 36 B (one of re/im plane).
// 16B pieces cover bytes 0..4095 (chunks 0..6 full + chunk 7 head);
// 2 x 4B ops cover chunk 7 bytes 64..575 (tail 512 B).
__device__ __forceinline__ void stage_slab(const char* __restrict__ base,
                                           char* lds, int wsite, int lane)
{
    #pragma unroll
    for (int k = 0; k < 4; k++) {
        int p   = k * 64 + lane;            // 16B piece index 0..255
        int c   = p / 36;                   // feature chunk 0..7 (576 B each)
        int off = (p - c * 36) * 16;        // byte offset within chunk
        const char* g = base + (size_t)(c * NSITES + wsite) * 36 + off;
        GLDS16(g, lds + k * 1024);
    }
    #pragma unroll
    for (int k = 0; k < 2; k++) {
        int off = 64 + 4 * (k * 64 + lane); // chunk 7, bytes 64..572
        const char* g = base + (size_t)(7 * NSITES + wsite) * 36 + off;
        GLDS4(g, lds + 4096 + k * 256);
    }
}

// V = E*M column product using the 8-DOF anti-hermitian E:
//  E = [[i*ed0, er01+i*ei01, er02+i*ei02],
//       [-er01+i*ei01, i*ed1, er12+i*ei12],
//       [-er02+i*ei02, -er12+i*ei12, i*ed2]]
#define ECOL(m0, m1, m2, v0, v1, v2) do { \
    v0.re = fmaf(-ed0, m0.im, fmaf(er01, m1.re, fmaf(-ei01, m1.im, fmaf(er02, m2.re, -(ei02 * m2.im))))); \
    v0.im = fmaf( ed0, m0.re, fmaf(er01, m1.im, fmaf( ei01, m1.re, fmaf(er02, m2.im,  (ei02 * m2.re))))); \
    v1.re = fmaf(-er01, m0.re, fmaf(-ei01, m0.im, fmaf(-ed1, m1.im, fmaf(er12, m2.re, -(ei12 * m2.im))))); \
    v1.im = fmaf(-er01, m0.im, fmaf( ei01, m0.re, fmaf( ed1, m1.re, fmaf(er12, m2.im,  (ei12 * m2.re))))); \
    v2.re = fmaf(-er02, m0.re, fmaf(-ei02, m0.im, fmaf(-er12, m1.re, fmaf(-ei12, m1.im, -(ed2 * m2.im))))); \
    v2.im = fmaf(-er02, m0.im, fmaf( ei02, m0.re, fmaf(-er12, m1.im, fmaf( ei12, m1.re,  (ed2 * m2.re))))); \
} while (0)

// real part of g0*m + g1*v + g2*z
#define OCOMB(m, v, z) \
    fmaf(g0.re, m.re, fmaf(-g0.im, m.im, fmaf(g1.re, v.re, fmaf(-g1.im, v.im, \
    fmaf(g2.re, z.re, -(g2.im * z.im))))))

// Block = 256 thr = 4 waves, 64 sites, all 4 mu. Wave-private two-phase LDS
// staging (re plane, then im plane into the SAME 4608-B slab): 18,432 B/block
// -> LDS permits 8 blocks/CU.
//
// launch_bounds NOTE (measured): (256,8) -> VGPR capped 64, catastrophic spill
// (WRITE 155 MB, 110 us). (256,6) -> allocator converged to 40 VGPR *with*
// 30 MB of spill traffic (48.7 MB writes, 60 us) — waves-per-eu pressure mode
// over-spills. (256,4) is the proven-clean regime (R0: 64 VGPR, zero scratch,
// on heavier code). Runtime occupancy follows ACTUAL VGPR count, so <=64 VGPR
// still yields 8 blocks/CU with the halved LDS.
__global__ __launch_bounds__(256, 4) void lge_exp_kernel(
    const float* __restrict__ U_re, const float* __restrict__ U_im,
    const float* __restrict__ W_re, const float* __restrict__ W_im,
    const float* __restrict__ ahw,  float* __restrict__ out)
{
    __shared__ __align__(16) float Wl[4 * 1152];   // 4 waves x 4608 B = 18,432 B

    const int tid   = threadIdx.x;
    const int w     = tid >> 6;        // wave id in block
    const int lane  = tid & 63;
    const int site0 = blockIdx.x << 6; // 64 sites per block
    const int wsite = site0 + 16 * w;

    float* ldsw = Wl + w * 1152;

    // ---- phase 1 staging: W_re slab (6 DMA ops) ----
    stage_slab((const char*)W_re, (char*)ldsw, wsite, lane);

    const int siteL = lane >> 2;               // 0..15 within wave tile
    const int mu    = lane & 3;
    const int gsite = wsite + siteL;

    // ahw row for this mu (drained by the same vmcnt wait)
    const float4* ahw4 = (const float4*)ahw;
    float4 wlo = ahw4[mu * 2], whi = ahw4[mu * 2 + 1];
    const float wfv[8] = { wlo.x, wlo.y, wlo.z, wlo.w, whi.x, whi.y, whi.z, whi.w };

    asm volatile("s_waitcnt vmcnt(0)" ::: "memory");   // drain W_re DMA (+ ahw)

    // ---- E real part: antisymmetric, 3 DOF. Re(W-W^dag) has zero diagonal
    //      and no trace correction -> only 3 accumulators, 6 LDS reads/feature.
    const float* wp = ldsw + siteL * 9;        // + f*144
    float er01 = 0.f, er02 = 0.f, er12 = 0.f;
    #pragma unroll
    for (int f = 0; f < 8; f++) {
        const float* r = wp + f * 144;
        float wf = wfv[f];
        er01 = fmaf(wf, r[1] - r[3], er01);
        er02 = fmaf(wf, r[2] - r[6], er02);
        er12 = fmaf(wf, r[5] - r[7], er12);
    }

    // all phase-1 ds_reads must retire before the W_im DMA overwrites the slab
    asm volatile("s_waitcnt lgkmcnt(0)" ::: "memory");

    // ---- phase 2 staging: W_im slab into the same buffer ----
    stage_slab((const char*)W_im, (char*)ldsw, wsite, lane);

    asm volatile("s_waitcnt vmcnt(0)" ::: "memory");   // drain W_im DMA

    // ---- E imag part: symmetric traceless, 5 DOF. Raw-accumulate 9 sums,
    //      combine once at the end.
    float a0=0.f,a1=0.f,a2=0.f,a3=0.f,a4=0.f,a5=0.f,a6=0.f,a7=0.f,a8=0.f;
    #pragma unroll
    for (int f = 0; f < 8; f++) {
        const float* r = wp + f * 144;
        float wf = wfv[f];
        a0 = fmaf(wf, r[0], a0); a1 = fmaf(wf, r[1], a1); a2 = fmaf(wf, r[2], a2);
        a3 = fmaf(wf, r[3], a3); a4 = fmaf(wf, r[4], a4); a5 = fmaf(wf, r[5], a5);
        a6 = fmaf(wf, r[6], a6); a7 = fmaf(wf, r[7], a7); a8 = fmaf(wf, r[8], a8);
    }

    // ---- U loads issued HERE: in flight under the whole Taylor/squaring chain
    //      (true prefetch — no vmcnt drain between issue and use), and their
    //      18-reg live range no longer spans the E computation.
    const int ub = (mu * NSITES + gsite) * 9;
    float ur[9], ui[9];
    ld9(U_re + ub, ur);
    ld9(U_im + ub, ui);

    const float ei01 = a1 + a3, ei02 = a2 + a6, ei12 = a5 + a7;
    const float t3  = (a0 + a4 + a8) * (2.f / 3.f);
    const float ed0 = fmaf(2.f, a0, -t3);
    const float ed1 = fmaf(2.f, a4, -t3);
    const float ed2 = fmaf(2.f, a8, -t3);       // == -ed0-ed1

    // ---- ||E||_F^2 ; p = tr(E^2)/2 = -r2/2 (REAL, free) ----
    float r2 = fmaf(er01, er01, fmaf(er02, er02, fmaf(er12, er12,
               fmaf(ei01, ei01, fmaf(ei02, ei02, ei12 * ei12)))));
    r2 = fmaf(2.f, r2, fmaf(ed0, ed0, fmaf(ed1, ed1, ed2 * ed2)));

    // ---- q = det(E) = -i*det(H), H = -iE hermitian -> q purely imaginary ----
    // h01=(ei01,-er01) h02=(ei02,-er02) h12=(ei12,-er12), diag = ed*
    const float n01 = fmaf(ei01, ei01, er01 * er01);
    const float n02 = fmaf(ei02, ei02, er02 * er02);
    const float n12 = fmaf(ei12, ei12, er12 * er12);
    const float zre = fmaf(ei01, ei12, -(er01 * er12));   // Re(h01*h12)
    const float zim = -fmaf(ei01, er12, er01 * ei12);     // Im(h01*h12)
    const float detH = ed0 * ed1 * ed2
                     + 2.f * fmaf(zre, ei02, -(zim * er02))
                     - fmaf(ed0, n12, fmaf(ed1, n02, ed2 * n01));

    // ---- scaling: 2^sc >= 2*||E||_F >= 2*rho(E), from exponent bits of r2 ----
    int e; (void)frexpf(r2, &e);                 // r2 = m*2^e, m in [0.5,1)
    int sc = (e <= -2) ? 0 : min(1 + ((e + 1) >> 1), 40);
    const float inv  = __int_as_float((127 - sc) << 23);   // 2^-sc
    const float inv2 = inv * inv;
    const float px   = -0.5f * r2 * inv2;        // p of scaled X (real)
    const float qxi  = -detH * (inv2 * inv);     // q of scaled X = i*qxi

    // ---- Taylor of exp(X) in coefficient space (p real, q imaginary) ----
    cplx T0 = {1.f, 0.f}, T1 = {0.f, 0.f}, T2 = {0.f, 0.f};
    cplx S0 = {1.f, 0.f}, S1 = {0.f, 0.f}, S2 = {0.f, 0.f};
    #pragma unroll
    for (int n = 1; n <= 10; n++) {
        float c  = 1.f / (float)n;               // folds to a literal
        float qc = qxi * c;
        cplx nT0 = { -qc * T2.im, qc * T2.re };
        cplx nT1 = { c * fmaf(px, T2.re, T0.re), c * fmaf(px, T2.im, T0.im) };
        cplx nT2 = { c * T1.re, c * T1.im };
        T0 = nT0; T1 = nT1; T2 = nT2;
        S0 = cadd(S0, T0); S1 = cadd(S1, T1); S2 = cadd(S2, T2);
    }

    // ---- repeated squaring in coefficient space ----
    const float q2 = 2.f * qxi;
    for (int k = 0; k < sc; k++) {
        cplx f0 = S0, f1 = S1, f2 = S2;
        cplx f12 = cmul(f1, f2);
        cplx f01 = cmul(f0, f1);
        cplx f02 = cmul(f0, f2);
        float f00re = fmaf(f0.re, f0.re, -(f0.im * f0.im)), f00im = 2.f * f0.re * f0.im;
        float f11re = fmaf(f1.re, f1.re, -(f1.im * f1.im)), f11im = 2.f * f1.re * f1.im;
        float f22re = fmaf(f2.re, f2.re, -(f2.im * f2.im)), f22im = 2.f * f2.re * f2.im;
        S0.re = fmaf(-q2, f12.im, f00re);
        S0.im = fmaf( q2, f12.re, f00im);
        S1.re = fmaf(-qxi, f22im, 2.f * fmaf(px, f12.re, f01.re));
        S1.im = fmaf( qxi, f22re, 2.f * fmaf(px, f12.im, f01.im));
        S2.re = fmaf(px, f22re, fmaf(2.f, f02.re, f11re));
        S2.im = fmaf(px, f22im, fmaf(2.f, f02.im, f11im));
    }
    const cplx g0 = S0;
    const cplx g1 = { S1.re * inv,  S1.im * inv  };
    const cplx g2 = { S2.re * inv2, S2.im * inv2 };

    // ---- apply: out = Re[ g0 U + g1 (E U) + g2 (E (E U)) ], column-wise ----
    float o[9];
    #pragma unroll
    for (int b = 0; b < 3; b++) {
        cplx m0 = { ur[b],     ui[b]     };
        cplx m1 = { ur[3 + b], ui[3 + b] };
        cplx m2 = { ur[6 + b], ui[6 + b] };
        cplx v0, v1, v2, z0, z1, z2;
        ECOL(m0, m1, m2, v0, v1, v2);   // V col = E * U col
        ECOL(v0, v1, v2, z0, z1, z2);   // Z col = E * V col
        o[b]     = OCOMB(m0, v0, z0);
        o[3 + b] = OCOMB(m1, v1, z1);
        o[6 + b] = OCOMB(m2, v2, z2);
    }

    float* ob = out + ub;
    *(f3*)(ob)     = { o[0], o[1], o[2] };
    *(f3*)(ob + 3) = { o[3], o[4], o[5] };
    *(f3*)(ob + 6) = { o[6], o[7], o[8] };
}

extern "C" void kernel_launch(void* const* d_in, const int* in_sizes, int n_in,
                              void* d_out, int out_size, void* d_ws, size_t ws_size,
                              hipStream_t stream) {
    const float* U_re = (const float*)d_in[0];
    const float* U_im = (const float*)d_in[1];
    const float* W_re = (const float*)d_in[2];
    const float* W_im = (const float*)d_in[3];
    const float* ahw  = (const float*)d_in[4];
    float* out = (float*)d_out;
    // 2048 blocks x 64 sites; each block computes all 4 mu for its sites
    lge_exp_kernel<<<dim3(NSITES / 64), dim3(256), 0, stream>>>(
        U_re, U_im, W_re, W_im, ahw, out);
}

// Round 4
// 145.490 us; speedup vs baseline: 1.4369x; 1.0005x over previous
//
#include <hip/hip_runtime.h>
#include <math.h>

#define NSITES 131072      // 32*16*16*16

struct cplx { float re, im; };

__device__ __forceinline__ cplx cadd(cplx a, cplx b) { return {a.re + b.re, a.im + b.im}; }
__device__ __forceinline__ cplx cmul(cplx a, cplx b) {
    return { fmaf(a.re, b.re, -(a.im * b.im)), fmaf(a.re, b.im, a.im * b.re) };
}

// 12-byte vector load (global_load_dwordx3); rows are 36 B so only 4B-aligned
struct __attribute__((aligned(4))) f3 { float x, y, z; };
__device__ __forceinline__ f3 ld3(const float* __restrict__ p) { return *(const f3*)p; }
__device__ __forceinline__ void ld9(const float* __restrict__ p, float* r) {
    f3 a = *(const f3*)p, b = *(const f3*)(p + 3), c = *(const f3*)(p + 6);
    r[0] = a.x; r[1] = a.y; r[2] = a.z;
    r[3] = b.x; r[4] = b.y; r[5] = b.z;
    r[6] = c.x; r[7] = c.y; r[8] = c.z;
}

// V = E*M column product using the 8-DOF anti-hermitian E:
//  E = [[i*ed0, er01+i*ei01, er02+i*ei02],
//       [-er01+i*ei01, i*ed1, er12+i*ei12],
//       [-er02+i*ei02, -er12+i*ei12, i*ed2]]
#define ECOL(m0, m1, m2, v0, v1, v2) do { \
    v0.re = fmaf(-ed0, m0.im, fmaf(er01, m1.re, fmaf(-ei01, m1.im, fmaf(er02, m2.re, -(ei02 * m2.im))))); \
    v0.im = fmaf( ed0, m0.re, fmaf(er01, m1.im, fmaf( ei01, m1.re, fmaf(er02, m2.im,  (ei02 * m2.re))))); \
    v1.re = fmaf(-er01, m0.re, fmaf(-ei01, m0.im, fmaf(-ed1, m1.im, fmaf(er12, m2.re, -(ei12 * m2.im))))); \
    v1.im = fmaf(-er01, m0.im, fmaf( ei01, m0.re, fmaf( ed1, m1.re, fmaf(er12, m2.im,  (ei12 * m2.re))))); \
    v2.re = fmaf(-er02, m0.re, fmaf(-ei02, m0.im, fmaf(-er12, m1.re, fmaf(-ei12, m1.im, -(ed2 * m2.im))))); \
    v2.im = fmaf(-er02, m0.im, fmaf( ei02, m0.re, fmaf(-er12, m1.im, fmaf( ei12, m1.re,  (ed2 * m2.re))))); \
} while (0)

// real part of g0*m + g1*v + g2*z
#define OCOMB(m, v, z) \
    fmaf(g0.re, m.re, fmaf(-g0.im, m.im, fmaf(g1.re, v.re, fmaf(-g1.im, v.im, \
    fmaf(g2.re, z.re, -(g2.im * z.im))))))

// NO LDS staging. Each lane owns one (site, mu); the 4 mu-lanes of a site are
// adjacent lanes (mu = gid&3) issuing IDENTICAL W addresses -> the TA
// coalescer merges them within each vector-mem instruction, so W HBM traffic
// is the same as the LDS-staged version, with zero vmcnt(0)/lgkmcnt(0) walls.
// The unrolled 8-feature loop lets the compiler keep a continuous stream of
// global loads in flight (incremental vmcnt waits) instead of the measured
// burst->drain->compute lockstep (avg ~6 outstanding reqs/CU, VALUBusy 20%).
//
// launch_bounds NOTE (measured): (256,8) -> 64-VGPR cap, catastrophic spill
// (WRITE 155 MB). (256,6) -> allocator over-spilled at 40 VGPR (WRITE 48.7 MB).
// (256,4) is the proven-clean regime (R0/R3: zero scratch).
__global__ __launch_bounds__(256, 4) void lge_exp_kernel(
    const float* __restrict__ U_re, const float* __restrict__ U_im,
    const float* __restrict__ W_re, const float* __restrict__ W_im,
    const float* __restrict__ ahw,  float* __restrict__ out)
{
    const int gid   = blockIdx.x * 256 + threadIdx.x;
    const int gsite = gid >> 2;        // 0..131071
    const int mu    = gid & 3;

    // ahw row for this mu: two aligned float4 loads
    const float4* ahw4 = (const float4*)ahw;
    float4 wlo = ahw4[mu * 2], whi = ahw4[mu * 2 + 1];
    const float wfv[8] = { wlo.x, wlo.y, wlo.z, wlo.w, whi.x, whi.y, whi.z, whi.w };

    const size_t sb = (size_t)gsite * 9;   // float offset of site within one feature plane

    // ---- E accumulation straight from global, feature-unrolled ----
    // E real part (antisymmetric, 3 DOF) needs only W_re elements 1,2,3,5,6,7
    // -> two dwordx3 per feature. E imag part needs all 9 of W_im.
    float er01 = 0.f, er02 = 0.f, er12 = 0.f;
    float a0=0.f,a1=0.f,a2=0.f,a3=0.f,a4=0.f,a5=0.f,a6=0.f,a7=0.f,a8=0.f;
    #pragma unroll
    for (int f = 0; f < 8; f++) {
        const float* pr = W_re + (size_t)f * (NSITES * 9) + sb;
        const float* pi = W_im + (size_t)f * (NSITES * 9) + sb;
        f3 q = ld3(pr + 1);            // w1 w2 w3
        f3 s = ld3(pr + 5);            // w5 w6 w7
        float wi[9];
        ld9(pi, wi);
        const float wf = wfv[f];
        er01 = fmaf(wf, q.x - q.z, er01);   // w1 - w3
        er02 = fmaf(wf, q.y - s.y, er02);   // w2 - w6
        er12 = fmaf(wf, s.x - s.z, er12);   // w5 - w7
        a0 = fmaf(wf, wi[0], a0); a1 = fmaf(wf, wi[1], a1); a2 = fmaf(wf, wi[2], a2);
        a3 = fmaf(wf, wi[3], a3); a4 = fmaf(wf, wi[4], a4); a5 = fmaf(wf, wi[5], a5);
        a6 = fmaf(wf, wi[6], a6); a7 = fmaf(wf, wi[7], a7); a8 = fmaf(wf, wi[8], a8);
    }

    // ---- U loads issued here: in flight under the whole Taylor/squaring chain
    const int ub = (mu * NSITES + gsite) * 9;
    float ur[9], ui[9];
    ld9(U_re + ub, ur);
    ld9(U_im + ub, ui);

    const float ei01 = a1 + a3, ei02 = a2 + a6, ei12 = a5 + a7;
    const float t3  = (a0 + a4 + a8) * (2.f / 3.f);
    const float ed0 = fmaf(2.f, a0, -t3);
    const float ed1 = fmaf(2.f, a4, -t3);
    const float ed2 = fmaf(2.f, a8, -t3);       // == -ed0-ed1

    // ---- ||E||_F^2 ; p = tr(E^2)/2 = -r2/2 (REAL, free) ----
    float r2 = fmaf(er01, er01, fmaf(er02, er02, fmaf(er12, er12,
               fmaf(ei01, ei01, fmaf(ei02, ei02, ei12 * ei12)))));
    r2 = fmaf(2.f, r2, fmaf(ed0, ed0, fmaf(ed1, ed1, ed2 * ed2)));

    // ---- q = det(E) = -i*det(H), H = -iE hermitian -> q purely imaginary ----
    const float n01 = fmaf(ei01, ei01, er01 * er01);
    const float n02 = fmaf(ei02, ei02, er02 * er02);
    const float n12 = fmaf(ei12, ei12, er12 * er12);
    const float zre = fmaf(ei01, ei12, -(er01 * er12));   // Re(h01*h12)
    const float zim = -fmaf(ei01, er12, er01 * ei12);     // Im(h01*h12)
    const float detH = ed0 * ed1 * ed2
                     + 2.f * fmaf(zre, ei02, -(zim * er02))
                     - fmaf(ed0, n12, fmaf(ed1, n02, ed2 * n01));

    // ---- scaling: 2^sc >= 2*||E||_F >= 2*rho(E), from exponent bits of r2 ----
    int e; (void)frexpf(r2, &e);                 // r2 = m*2^e, m in [0.5,1)
    int sc = (e <= -2) ? 0 : min(1 + ((e + 1) >> 1), 40);
    const float inv  = __int_as_float((127 - sc) << 23);   // 2^-sc
    const float inv2 = inv * inv;
    const float px   = -0.5f * r2 * inv2;        // p of scaled X (real)
    const float qxi  = -detH * (inv2 * inv);     // q of scaled X = i*qxi

    // ---- Taylor of exp(X) in coefficient space (p real, q imaginary) ----
    cplx T0 = {1.f, 0.f}, T1 = {0.f, 0.f}, T2 = {0.f, 0.f};
    cplx S0 = {1.f, 0.f}, S1 = {0.f, 0.f}, S2 = {0.f, 0.f};
    #pragma unroll
    for (int n = 1; n <= 10; n++) {
        float c  = 1.f / (float)n;               // folds to a literal
        float qc = qxi * c;
        cplx nT0 = { -qc * T2.im, qc * T2.re };
        cplx nT1 = { c * fmaf(px, T2.re, T0.re), c * fmaf(px, T2.im, T0.im) };
        cplx nT2 = { c * T1.re, c * T1.im };
        T0 = nT0; T1 = nT1; T2 = nT2;
        S0 = cadd(S0, T0); S1 = cadd(S1, T1); S2 = cadd(S2, T2);
    }

    // ---- repeated squaring in coefficient space ----
    const float q2 = 2.f * qxi;
    for (int k = 0; k < sc; k++) {
        cplx f0 = S0, f1 = S1, f2 = S2;
        cplx f12 = cmul(f1, f2);
        cplx f01 = cmul(f0, f1);
        cplx f02 = cmul(f0, f2);
        float f00re = fmaf(f0.re, f0.re, -(f0.im * f0.im)), f00im = 2.f * f0.re * f0.im;
        float f11re = fmaf(f1.re, f1.re, -(f1.im * f1.im)), f11im = 2.f * f1.re * f1.im;
        float f22re = fmaf(f2.re, f2.re, -(f2.im * f2.im)), f22im = 2.f * f2.re * f2.im;
        S0.re = fmaf(-q2, f12.im, f00re);
        S0.im = fmaf( q2, f12.re, f00im);
        S1.re = fmaf(-qxi, f22im, 2.f * fmaf(px, f12.re, f01.re));
        S1.im = fmaf( qxi, f22re, 2.f * fmaf(px, f12.im, f01.im));
        S2.re = fmaf(px, f22re, fmaf(2.f, f02.re, f11re));
        S2.im = fmaf(px, f22im, fmaf(2.f, f02.im, f11im));
    }
    const cplx g0 = S0;
    const cplx g1 = { S1.re * inv,  S1.im * inv  };
    const cplx g2 = { S2.re * inv2, S2.im * inv2 };

    // ---- apply: out = Re[ g0 U + g1 (E U) + g2 (E (E U)) ], column-wise ----
    float o[9];
    #pragma unroll
    for (int b = 0; b < 3; b++) {
        cplx m0 = { ur[b],     ui[b]     };
        cplx m1 = { ur[3 + b], ui[3 + b] };
        cplx m2 = { ur[6 + b], ui[6 + b] };
        cplx v0, v1, v2, z0, z1, z2;
        ECOL(m0, m1, m2, v0, v1, v2);   // V col = E * U col
        ECOL(v0, v1, v2, z0, z1, z2);   // Z col = E * V col
        o[b]     = OCOMB(m0, v0, z0);
        o[3 + b] = OCOMB(m1, v1, z1);
        o[6 + b] = OCOMB(m2, v2, z2);
    }

    float* ob = out + ub;
    *(f3*)(ob)     = { o[0], o[1], o[2] };
    *(f3*)(ob + 3) = { o[3], o[4], o[5] };
    *(f3*)(ob + 6) = { o[6], o[7], o[8] };
}

extern "C" void kernel_launch(void* const* d_in, const int* in_sizes, int n_in,
                              void* d_out, int out_size, void* d_ws, size_t ws_size,
                              hipStream_t stream) {
    const float* U_re = (const float*)d_in[0];
    const float* U_im = (const float*)d_in[1];
    const float* W_re = (const float*)d_in[2];
    const float* W_im = (const float*)d_in[3];
    const float* ahw  = (const float*)d_in[4];
    float* out = (float*)d_out;
    // one lane per (site, mu): 524288 lanes = 2048 blocks x 256
    lge_exp_kernel<<<dim3(NSITES * 4 / 256), dim3(256), 0, stream>>>(
        U_re, U_im, W_re, W_im, ahw, out);
}

// Round 5
// 144.062 us; speedup vs baseline: 1.4512x; 1.0099x over previous
//
#include <hip/hip_runtime.h>
#include <math.h>

#define NSITES 131072      // 32*16*16*16

struct cplx { float re, im; };

__device__ __forceinline__ cplx cadd(cplx a, cplx b) { return {a.re + b.re, a.im + b.im}; }
__device__ __forceinline__ cplx cmul(cplx a, cplx b) {
    return { fmaf(a.re, b.re, -(a.im * b.im)), fmaf(a.re, b.im, a.im * b.re) };
}

// 12-byte vector load (global_load_dwordx3); rows are 36 B so only 4B-aligned
struct __attribute__((aligned(4))) f3 { float x, y, z; };
__device__ __forceinline__ f3 ld3(const float* __restrict__ p) { return *(const f3*)p; }
__device__ __forceinline__ void ld9(const float* __restrict__ p, float* r) {
    f3 a = *(const f3*)p, b = *(const f3*)(p + 3), c = *(const f3*)(p + 6);
    r[0] = a.x; r[1] = a.y; r[2] = a.z;
    r[3] = b.x; r[4] = b.y; r[5] = b.z;
    r[6] = c.x; r[7] = c.y; r[8] = c.z;
}

// 4-lane-group broadcast: lane i reads from lane (i & 0x1C) | g  (g = 0..3).
// BitMode ds_swizzle imm = (xor<<10)|(or<<5)|and with and=0x1C, or=g, xor=0.
#define SWZ(imm, x) __int_as_float(__builtin_amdgcn_ds_swizzle(__float_as_int(x), imm))

// Accumulate feature broadcast from group-lane g (imm literal) into the 9 E sums.
// arr = source lane's pre-reduced 9 floats: {rd01, rd02, rd12, si01, si02, si12, i0, i4, i8}
#define ACCF(arr, wf, imm) do { \
    er01 = fmaf(wf, SWZ(imm, arr[0]), er01); \
    er02 = fmaf(wf, SWZ(imm, arr[1]), er02); \
    er12 = fmaf(wf, SWZ(imm, arr[2]), er12); \
    si01 = fmaf(wf, SWZ(imm, arr[3]), si01); \
    si02 = fmaf(wf, SWZ(imm, arr[4]), si02); \
    si12 = fmaf(wf, SWZ(imm, arr[5]), si12); \
    dd0  = fmaf(wf, SWZ(imm, arr[6]), dd0); \
    dd4  = fmaf(wf, SWZ(imm, arr[7]), dd4); \
    dd8  = fmaf(wf, SWZ(imm, arr[8]), dd8); \
} while (0)

// V = E*M column product using the 8-DOF anti-hermitian E:
//  E = [[i*ed0, er01+i*ei01, er02+i*ei02],
//       [-er01+i*ei01, i*ed1, er12+i*ei12],
//       [-er02+i*ei02, -er12+i*ei12, i*ed2]]
#define ECOL(m0, m1, m2, v0, v1, v2) do { \
    v0.re = fmaf(-ed0, m0.im, fmaf(er01, m1.re, fmaf(-ei01, m1.im, fmaf(er02, m2.re, -(ei02 * m2.im))))); \
    v0.im = fmaf( ed0, m0.re, fmaf(er01, m1.im, fmaf( ei01, m1.re, fmaf(er02, m2.im,  (ei02 * m2.re))))); \
    v1.re = fmaf(-er01, m0.re, fmaf(-ei01, m0.im, fmaf(-ed1, m1.im, fmaf(er12, m2.re, -(ei12 * m2.im))))); \
    v1.im = fmaf(-er01, m0.im, fmaf( ei01, m0.re, fmaf( ed1, m1.re, fmaf(er12, m2.im,  (ei12 * m2.re))))); \
    v2.re = fmaf(-er02, m0.re, fmaf(-ei02, m0.im, fmaf(-er12, m1.re, fmaf(-ei12, m1.im, -(ed2 * m2.im))))); \
    v2.im = fmaf(-er02, m0.im, fmaf( ei02, m0.re, fmaf(-er12, m1.im, fmaf( ei12, m1.re,  (ed2 * m2.re))))); \
} while (0)

// real part of g0*m + g1*v + g2*z
#define OCOMB(m, v, z) \
    fmaf(g0.re, m.re, fmaf(-g0.im, m.im, fmaf(g1.re, v.re, fmaf(-g1.im, v.im, \
    fmaf(g2.re, z.re, -(g2.im * z.im))))))

// COOPERATIVE mu-quad loading. R0/R3/R4 all measured ~42-45 us with VALUBusy
// ~20%, occupancy ~35%: per-wave lifetime ~15 us = ~50 VMEM ops x serialized
// latency (VGPR-minimized codegen keeps ~1 load in flight). The 4 mu-lanes of
// a site were loading IDENTICAL W data 4x (issue count, not bytes). Now each
// lane loads 2 of the 8 features (f = mu, mu+4: 10 loads, one latency round),
// pre-reduces each feature to the 9 floats E consumes, and the 4-lane group
// shares them via static ds_swizzle broadcasts (72 swizzles + 72 FMAs, VALU
// pipe, no LDS, no walls). Per-lane VMEM: 51 -> ~21.
//
// launch_bounds NOTE (measured): (256,8) 64-VGPR cap -> 155 MB spill;
// (256,6) pressure mode -> 48.7 MB spill; (256,4) clean (R0/R3/R4).
__global__ __launch_bounds__(256, 4) void lge_exp_kernel(
    const float* __restrict__ U_re, const float* __restrict__ U_im,
    const float* __restrict__ W_re, const float* __restrict__ W_im,
    const float* __restrict__ ahw,  float* __restrict__ out)
{
    const int gid   = blockIdx.x * 256 + threadIdx.x;
    const int gsite = gid >> 2;        // 0..131071 (4-lane group shares a site)
    const int mu    = gid & 3;

    // ahw row for this mu: two aligned float4 loads
    const float4* ahw4 = (const float4*)ahw;
    float4 wlo = ahw4[mu * 2], whi = ahw4[mu * 2 + 1];
    const float wfv[8] = { wlo.x, wlo.y, wlo.z, wlo.w, whi.x, whi.y, whi.z, whi.w };

    const size_t sb = (size_t)gsite * 9;   // float offset within one feature plane

    // ---- this lane's two features: fA = mu, fB = mu+4 (10 loads total) ----
    const float* prA = W_re + (size_t)mu * (NSITES * 9) + sb;
    const float* piA = W_im + (size_t)mu * (NSITES * 9) + sb;
    const float* prB = W_re + (size_t)(mu + 4) * (NSITES * 9) + sb;
    const float* piB = W_im + (size_t)(mu + 4) * (NSITES * 9) + sb;

    f3 qA = ld3(prA + 1), sA = ld3(prA + 5);   // re elements 1,2,3 / 5,6,7
    float iA[9]; ld9(piA, iA);
    f3 qB = ld3(prB + 1), sB = ld3(prB + 5);
    float iB[9]; ld9(piB, iB);

    // ---- U loads issued alongside: compiler's counted vmcnt leaves them in
    //      flight under the whole E + Taylor chain; consumed at the end.
    const int ub = (mu * NSITES + gsite) * 9;
    float ur[9], ui[9];
    ld9(U_re + ub, ur);
    ld9(U_im + ub, ui);

    // ---- owner pre-reduction: 9 floats per feature, the exact E inputs.
    // re part of W-W^dag is antisymmetric (3 diffs); im part is symmetric:
    // off-diag pairs SUM (weighting is linear, so pre-sum before broadcast).
    float fa[9] = { qA.x - qA.z,  qA.y - sA.y,  sA.x - sA.z,
                    iA[1] + iA[3], iA[2] + iA[6], iA[5] + iA[7],
                    iA[0], iA[4], iA[8] };
    float fb[9] = { qB.x - qB.z,  qB.y - sB.y,  sB.x - sB.z,
                    iB[1] + iB[3], iB[2] + iB[6], iB[5] + iB[7],
                    iB[0], iB[4], iB[8] };

    // ---- E accumulation: broadcast each feature from its owner lane ----
    float er01 = 0.f, er02 = 0.f, er12 = 0.f;
    float si01 = 0.f, si02 = 0.f, si12 = 0.f;
    float dd0 = 0.f, dd4 = 0.f, dd8 = 0.f;
    ACCF(fa, wfv[0], 0x1C);   // feature 0 from group-lane 0 (its fA)
    ACCF(fa, wfv[1], 0x3C);   // feature 1 from group-lane 1
    ACCF(fa, wfv[2], 0x5C);
    ACCF(fa, wfv[3], 0x7C);
    ACCF(fb, wfv[4], 0x1C);   // feature 4 from group-lane 0 (its fB)
    ACCF(fb, wfv[5], 0x3C);
    ACCF(fb, wfv[6], 0x5C);
    ACCF(fb, wfv[7], 0x7C);

    const float ei01 = si01, ei02 = si02, ei12 = si12;
    const float t3  = (dd0 + dd4 + dd8) * (2.f / 3.f);
    const float ed0 = fmaf(2.f, dd0, -t3);
    const float ed1 = fmaf(2.f, dd4, -t3);
    const float ed2 = fmaf(2.f, dd8, -t3);       // == -ed0-ed1

    // ---- ||E||_F^2 ; p = tr(E^2)/2 = -r2/2 (REAL, free) ----
    float r2 = fmaf(er01, er01, fmaf(er02, er02, fmaf(er12, er12,
               fmaf(ei01, ei01, fmaf(ei02, ei02, ei12 * ei12)))));
    r2 = fmaf(2.f, r2, fmaf(ed0, ed0, fmaf(ed1, ed1, ed2 * ed2)));

    // ---- q = det(E) = -i*det(H), H = -iE hermitian -> q purely imaginary ----
    const float n01 = fmaf(ei01, ei01, er01 * er01);
    const float n02 = fmaf(ei02, ei02, er02 * er02);
    const float n12 = fmaf(ei12, ei12, er12 * er12);
    const float zre = fmaf(ei01, ei12, -(er01 * er12));   // Re(h01*h12)
    const float zim = -fmaf(ei01, er12, er01 * ei12);     // Im(h01*h12)
    const float detH = ed0 * ed1 * ed2
                     + 2.f * fmaf(zre, ei02, -(zim * er02))
                     - fmaf(ed0, n12, fmaf(ed1, n02, ed2 * n01));

    // ---- scaling: 2^sc >= 2*||E||_F >= 2*rho(E), from exponent bits of r2 ----
    int e; (void)frexpf(r2, &e);                 // r2 = m*2^e, m in [0.5,1)
    int sc = (e <= -2) ? 0 : min(1 + ((e + 1) >> 1), 40);
    const float inv  = __int_as_float((127 - sc) << 23);   // 2^-sc
    const float inv2 = inv * inv;
    const float px   = -0.5f * r2 * inv2;        // p of scaled X (real)
    const float qxi  = -detH * (inv2 * inv);     // q of scaled X = i*qxi

    // ---- Taylor of exp(X) in coefficient space (p real, q imaginary) ----
    cplx T0 = {1.f, 0.f}, T1 = {0.f, 0.f}, T2 = {0.f, 0.f};
    cplx S0 = {1.f, 0.f}, S1 = {0.f, 0.f}, S2 = {0.f, 0.f};
    #pragma unroll
    for (int n = 1; n <= 10; n++) {
        float c  = 1.f / (float)n;               // folds to a literal
        float qc = qxi * c;
        cplx nT0 = { -qc * T2.im, qc * T2.re };
        cplx nT1 = { c * fmaf(px, T2.re, T0.re), c * fmaf(px, T2.im, T0.im) };
        cplx nT2 = { c * T1.re, c * T1.im };
        T0 = nT0; T1 = nT1; T2 = nT2;
        S0 = cadd(S0, T0); S1 = cadd(S1, T1); S2 = cadd(S2, T2);
    }

    // ---- repeated squaring in coefficient space ----
    const float q2 = 2.f * qxi;
    for (int k = 0; k < sc; k++) {
        cplx f0 = S0, f1 = S1, f2 = S2;
        cplx f12 = cmul(f1, f2);
        cplx f01 = cmul(f0, f1);
        cplx f02 = cmul(f0, f2);
        float f00re = fmaf(f0.re, f0.re, -(f0.im * f0.im)), f00im = 2.f * f0.re * f0.im;
        float f11re = fmaf(f1.re, f1.re, -(f1.im * f1.im)), f11im = 2.f * f1.re * f1.im;
        float f22re = fmaf(f2.re, f2.re, -(f2.im * f2.im)), f22im = 2.f * f2.re * f2.im;
        S0.re = fmaf(-q2, f12.im, f00re);
        S0.im = fmaf( q2, f12.re, f00im);
        S1.re = fmaf(-qxi, f22im, 2.f * fmaf(px, f12.re, f01.re));
        S1.im = fmaf( qxi, f22re, 2.f * fmaf(px, f12.im, f01.im));
        S2.re = fmaf(px, f22re, fmaf(2.f, f02.re, f11re));
        S2.im = fmaf(px, f22im, fmaf(2.f, f02.im, f11im));
    }
    const cplx g0 = S0;
    const cplx g1 = { S1.re * inv,  S1.im * inv  };
    const cplx g2 = { S2.re * inv2, S2.im * inv2 };

    // ---- apply: out = Re[ g0 U + g1 (E U) + g2 (E (E U)) ], column-wise ----
    float o[9];
    #pragma unroll
    for (int b = 0; b < 3; b++) {
        cplx m0 = { ur[b],     ui[b]     };
        cplx m1 = { ur[3 + b], ui[3 + b] };
        cplx m2 = { ur[6 + b], ui[6 + b] };
        cplx v0, v1, v2, z0, z1, z2;
        ECOL(m0, m1, m2, v0, v1, v2);   // V col = E * U col
        ECOL(v0, v1, v2, z0, z1, z2);   // Z col = E * V col
        o[b]     = OCOMB(m0, v0, z0);
        o[3 + b] = OCOMB(m1, v1, z1);
        o[6 + b] = OCOMB(m2, v2, z2);
    }

    float* ob = out + ub;
    *(f3*)(ob)     = { o[0], o[1], o[2] };
    *(f3*)(ob + 3) = { o[3], o[4], o[5] };
    *(f3*)(ob + 6) = { o[6], o[7], o[8] };
}

extern "C" void kernel_launch(void* const* d_in, const int* in_sizes, int n_in,
                              void* d_out, int out_size, void* d_ws, size_t ws_size,
                              hipStream_t stream) {
    const float* U_re = (const float*)d_in[0];
    const float* U_im = (const float*)d_in[1];
    const float* W_re = (const float*)d_in[2];
    const float* W_im = (const float*)d_in[3];
    const float* ahw  = (const float*)d_in[4];
    float* out = (float*)d_out;
    // one lane per (site, mu): 524288 lanes = 2048 blocks x 256
    lge_exp_kernel<<<dim3(NSITES * 4 / 256), dim3(256), 0, stream>>>(
        U_re, U_im, W_re, W_im, ahw, out);
}